// Round 7
// baseline (83.342 us; speedup 1.0000x reference)
//
#include <hip/hip_runtime.h>
#include <hip/hip_bf16.h>
#include <math.h>

typedef short short8 __attribute__((ext_vector_type(8)));
typedef float f32x4 __attribute__((ext_vector_type(4)));

#define NQ 32
#define NDOCS 8
#define QLEN 32
#define DLEN 200
#define DIM 128
#define MD 256           // total docs
#define HD_ROWS 208      // 13 tiles x 16 rows (200 real + 8 pad; pad masked)

__device__ __forceinline__ short f2bf(float x) {
    union { float f; unsigned u; } v; v.f = x;
    unsigned r = v.u + 0x7FFFu + ((v.u >> 16) & 1u);  // RNE
    return (short)(r >> 16);
}

__device__ __forceinline__ short8 cvt8(float4 f0, float4 f1) {
    short8 o;
    o[0] = f2bf(f0.x); o[1] = f2bf(f0.y); o[2] = f2bf(f0.z); o[3] = f2bf(f0.w);
    o[4] = f2bf(f1.x); o[5] = f2bf(f1.y); o[6] = f2bf(f1.z); o[7] = f2bf(f1.w);
    return o;
}

// hd fp32 -> bf16 in d_ws, 208-row doc stride. 819200 chunks of 8 elems.
__global__ __launch_bounds__(256) void convert_hd(const float* __restrict__ hd,
                                                  short* __restrict__ hdb) {
    unsigned c = blockIdx.x * 256 + threadIdx.x;       // 0..819199
    unsigned m = c / 3200u;                            // 3200 = 200 rows * 16 chunks
    unsigned rkc = c - m * 3200u;
    const float4* p = reinterpret_cast<const float4*>(hd) + (size_t)c * 2;
    reinterpret_cast<short8*>(hdb)[(size_t)m * (HD_ROWS * 16) + rkc] = cvt8(p[0], p[1]);
}

// One wave per (n,m) pair: 2048 blocks x 4 waves = 8192 waves, no LDS, no barriers.
// Block mapping: x=b&7 (XCD), j=b>>3; m=(j>>3)*8+x  -> all 8 blocks of doc m share
// one XCD's L2 (doc = 53KB bf16; 32 docs/XCD = 1.7MB < 4MB L2). n=(j&7)*4+wid.
// C = mfma(A=hd_frag, B=hq_frag): lane holds C[d=dt*16+lg*4+r][q=qt*16+lr].
__global__ __launch_bounds__(256, 4) void colbert_scores(const float* __restrict__ hq,
                                                         const short* __restrict__ hdb,
                                                         float* __restrict__ out) {
    const int tid = threadIdx.x;
    const int wid = tid >> 6, lane = tid & 63;
    const int lg = lane >> 4, lr = lane & 15;
    const int b = blockIdx.x;
    const int x = b & 7, j = b >> 3;
    const int m = ((j >> 3) << 3) | x;
    const int n = (j & 7) * 4 + wid;

    // B-fragments (hq[n], fp32 -> bf16 inline): 2 q-tiles x 4 k-slices = 32 VGPR
    short8 Bq[2][4];
    #pragma unroll
    for (int qt = 0; qt < 2; ++qt)
        #pragma unroll
        for (int s = 0; s < 4; ++s) {
            const float4* p = reinterpret_cast<const float4*>(
                hq + (size_t)(n * QLEN + qt * 16 + lr) * DIM + s * 32 + lg * 8);
            Bq[qt][s] = cvt8(p[0], p[1]);
        }

    // lane's A base: doc m, row lr, k-offset lg*8. Frag (dt,s) at +dt*2048 + s*32 elems.
    const short* ab = hdb + (size_t)m * (HD_ROWS * DIM) + (size_t)lr * DIM + lg * 8;

    float q0 = -INFINITY, q1 = -INFINITY;
    short8 A0[4], A1[4];

#define LOADA(BUF, DT)                                                            \
    {                                                                             \
        _Pragma("unroll")                                                         \
        for (int s = 0; s < 4; ++s)                                               \
            BUF[s] = *reinterpret_cast<const short8*>(ab + (DT) * 2048 + s * 32); \
    }

#define COMP(BUF, DT, MASKED)                                                     \
    {                                                                             \
        f32x4 a0 = {0.f, 0.f, 0.f, 0.f}, a1 = {0.f, 0.f, 0.f, 0.f};               \
        _Pragma("unroll")                                                         \
        for (int s = 0; s < 4; ++s) {                                             \
            a0 = __builtin_amdgcn_mfma_f32_16x16x32_bf16(BUF[s], Bq[0][s], a0, 0, 0, 0); \
            a1 = __builtin_amdgcn_mfma_f32_16x16x32_bf16(BUF[s], Bq[1][s], a1, 0, 0, 0); \
        }                                                                         \
        if (!(MASKED) || lg < 2) {                                                \
            q0 = fmaxf(q0, fmaxf(fmaxf(a0[0], a0[1]), fmaxf(a0[2], a0[3])));      \
            q1 = fmaxf(q1, fmaxf(fmaxf(a1[0], a1[1]), fmaxf(a1[2], a1[3])));      \
        }                                                                         \
    }

    // dt 0..12, double-buffered: 4 loads always in flight under the 8-MFMA compute
    LOADA(A0, 0);
    LOADA(A1, 1);
    #pragma unroll
    for (int t = 0; t < 5; ++t) {
        COMP(A0, 2 * t, false);
        LOADA(A0, 2 * t + 2);
        COMP(A1, 2 * t + 1, false);
        LOADA(A1, 2 * t + 3);
    }
    COMP(A0, 10, false);
    LOADA(A0, 12);
    COMP(A1, 11, false);
    COMP(A0, 12, true);   // rows 192..199 valid only for lg<2
#undef LOADA
#undef COMP

    // max over d: combine the 4 lg groups (lanes ^16, ^32)
    #pragma unroll
    for (int off = 16; off <= 32; off <<= 1) {
        q0 = fmaxf(q0, __shfl_xor(q0, off, 64));
        q1 = fmaxf(q1, __shfl_xor(q1, off, 64));
    }
    // mean over q: qt0 + qt1 (this lane's two q rows), then sum across the 16 lr lanes
    float s = q0 + q1;
    #pragma unroll
    for (int off = 1; off <= 8; off <<= 1) s += __shfl_xor(s, off, 64);
    if (lane == 0) out[(size_t)n * MD + m] = s * (1.0f / 32.0f);
}

// loss = mean_n( logsumexp(row_n) - row_n[8n] )
__global__ __launch_bounds__(256) void colbert_loss(const float* __restrict__ scores,
                                                    float* __restrict__ loss_out) {
    __shared__ float terms[NQ];
    const int tid = threadIdx.x;
    const int wid = tid >> 6, lane = tid & 63;
    for (int n = wid; n < NQ; n += 4) {
        const float* row = scores + n * MD;
        float v0 = row[lane], v1 = row[64 + lane], v2 = row[128 + lane], v3 = row[192 + lane];
        float mx = fmaxf(fmaxf(v0, v1), fmaxf(v2, v3));
        #pragma unroll
        for (int off = 1; off < 64; off <<= 1) mx = fmaxf(mx, __shfl_xor(mx, off, 64));
        float s = expf(v0 - mx) + expf(v1 - mx) + expf(v2 - mx) + expf(v3 - mx);
        #pragma unroll
        for (int off = 1; off < 64; off <<= 1) s += __shfl_xor(s, off, 64);
        if (lane == 0) terms[n] = (mx + logf(s)) - row[n * NDOCS];
    }
    __syncthreads();
    if (tid == 0) {
        float acc = 0.f;
        #pragma unroll
        for (int n = 0; n < NQ; ++n) acc += terms[n];
        loss_out[0] = acc * (1.0f / NQ);
    }
}

extern "C" void kernel_launch(void* const* d_in, const int* in_sizes, int n_in,
                              void* d_out, int out_size, void* d_ws, size_t ws_size,
                              hipStream_t stream) {
    const float* hq = (const float*)d_in[0];   // [32][32][128] f32
    const float* hd = (const float*)d_in[1];   // [256][200][128] f32
    float* out = (float*)d_out;                // 8192 scores + 1 loss
    short* hdb = (short*)d_ws;                 // 256 docs x 208 rows x 128 bf16 = 13.6 MB

    convert_hd<<<3200, 256, 0, stream>>>(hd, hdb);
    colbert_scores<<<2048, 256, 0, stream>>>(hq, hdb, out);
    colbert_loss<<<1, 256, 0, stream>>>(out, out + NQ * MD);
}

// Round 8
// 59.422 us; speedup vs baseline: 1.4025x; 1.4025x over previous
//
#include <hip/hip_runtime.h>
#include <hip/hip_bf16.h>
#include <math.h>

typedef short short8 __attribute__((ext_vector_type(8)));
typedef float f32x4 __attribute__((ext_vector_type(4)));

#define NQ 32
#define NDOCS 8
#define QLEN 32
#define DLEN 200
#define DIM 128
#define MD 256            // total docs
#define HD_ROWS 208       // 200 real + 8 zero pad rows
#define DOC_SHORTS (HD_ROWS * DIM)      // 26624 bf16 = 53248 B per doc
#define DOC_CHUNKS (HD_ROWS * 16)       // 3328 16B-chunks per doc

__device__ __forceinline__ short f2bf(float x) {
    union { float f; unsigned u; } v; v.f = x;
    unsigned r = v.u + 0x7FFFu + ((v.u >> 16) & 1u);  // RNE
    return (short)(r >> 16);
}

__device__ __forceinline__ short8 cvt8(float4 f0, float4 f1) {
    short8 o;
    o[0] = f2bf(f0.x); o[1] = f2bf(f0.y); o[2] = f2bf(f0.z); o[3] = f2bf(f0.w);
    o[4] = f2bf(f1.x); o[5] = f2bf(f1.y); o[6] = f2bf(f1.z); o[7] = f2bf(f1.w);
    return o;
}

// hd fp32 -> bf16, PRE-SWIZZLED in global (chunk kc -> kc ^ (row&7) within row),
// pad rows 200..207 zeroed. LDS staging then becomes a linear copy and the
// compute-side XOR'd ds_read math reads it conflict-free (2-way max).
__global__ __launch_bounds__(256) void convert_hd(const float* __restrict__ hd,
                                                  short* __restrict__ hdb) {
    unsigned c = blockIdx.x * 256 + threadIdx.x;       // global chunk id, < 851968
    unsigned m = c / DOC_CHUNKS;
    unsigned rc = c - m * DOC_CHUNKS;
    unsigned row = rc >> 4, kc = rc & 15;
    short8 o = {0, 0, 0, 0, 0, 0, 0, 0};
    if (row < DLEN) {
        const float4* p = reinterpret_cast<const float4*>(
            hd + ((size_t)m * DLEN + row) * DIM + kc * 8);
        o = cvt8(p[0], p[1]);
    }
    unsigned dst = m * DOC_CHUNKS + row * 16 + (kc ^ (row & 7));
    reinterpret_cast<short8*>(hdb)[dst] = o;
}

// Block (512 thr / 8 waves) = (doc m = b>>1, q-half = b&1). 2 blocks/CU, 4 waves/SIMD.
// Wave w: questions n0 = qhalf*16 + w*2 + {0,1}.
// C = mfma(A=hd_frag, B=hq_frag): lane holds C[d = dt*16 + lg*4 + r][q = qt*16 + lr].
// Live regs ~116; waves_per_eu(4,4) pins budget at 128 -> no spill possible.
__global__ __launch_bounds__(512)
__attribute__((amdgpu_waves_per_eu(4, 4)))
void colbert_scores(const float* __restrict__ hq,
                    const short* __restrict__ hdb,
                    float* __restrict__ out) {
    __shared__ short lds[DOC_SHORTS];   // 53248 B
    const int tid = threadIdx.x;
    const int b = blockIdx.x;
    const int m = b >> 1, qh = b & 1;
    const int wid = tid >> 6, lane = tid & 63;
    const int lg = lane >> 4, lr = lane & 15;
    const int n0 = qh * 16 + wid * 2;

    // ---- 1) issue the whole doc's loads (7 independent 16B loads/thread) ----
    const short8* doc = reinterpret_cast<const short8*>(hdb + (size_t)m * DOC_SHORTS);
    short8 st0 = doc[tid],          st1 = doc[tid + 512];
    short8 st2 = doc[tid + 1024],   st3 = doc[tid + 1536];
    short8 st4 = doc[tid + 2048],   st5 = doc[tid + 2560];
    short8 st6 = {0,0,0,0,0,0,0,0};
    const bool t7 = tid < 256;      // 3328 chunks total
    if (t7) st6 = doc[tid + 3072];

    // ---- 2) Bq from fp32 hq (L2-resident) while doc loads are in flight ----
    short8 Bq[2][2][4];
    #pragma unroll
    for (int nn = 0; nn < 2; ++nn)
        #pragma unroll
        for (int qt = 0; qt < 2; ++qt)
            #pragma unroll
            for (int s = 0; s < 4; ++s) {
                const float4* p = reinterpret_cast<const float4*>(
                    hq + (size_t)((n0 + nn) * QLEN + qt * 16 + lr) * DIM + s * 32 + lg * 8);
                Bq[nn][qt][s] = cvt8(p[0], p[1]);
            }

    // ---- 3) linear ds_write (data already swizzled in global), one barrier ----
    short8* ldsv = reinterpret_cast<short8*>(lds);
    ldsv[tid] = st0;         ldsv[tid + 512] = st1;
    ldsv[tid + 1024] = st2;  ldsv[tid + 1536] = st3;
    ldsv[tid + 2048] = st4;  ldsv[tid + 2560] = st5;
    if (t7) ldsv[tid + 3072] = st6;
    __syncthreads();

    // ---- 4) compute: 13 tiles x (4 ds_read_b128 + 16 MFMA) ----
    const char* ldsb = reinterpret_cast<const char*>(lds);
    int va[4];
    #pragma unroll
    for (int s = 0; s < 4; ++s)
        va[s] = lr * 256 + ((s * 64 + lg * 16) ^ ((lr & 7) << 4));

    float qmax[2][2];
    #pragma unroll
    for (int nn = 0; nn < 2; ++nn)
        #pragma unroll
        for (int qt = 0; qt < 2; ++qt) qmax[nn][qt] = -INFINITY;

#define STEP(DT, MASKED)                                                          \
    {                                                                             \
        f32x4 acc[2][2];                                                          \
        _Pragma("unroll")                                                         \
        for (int nn = 0; nn < 2; ++nn)                                            \
            _Pragma("unroll")                                                     \
            for (int qt = 0; qt < 2; ++qt) acc[nn][qt] = (f32x4){0.f,0.f,0.f,0.f};\
        _Pragma("unroll")                                                         \
        for (int s = 0; s < 4; ++s) {                                             \
            short8 A_ = *reinterpret_cast<const short8*>(&ldsb[va[s] + (DT) * 4096]); \
            _Pragma("unroll")                                                     \
            for (int nn = 0; nn < 2; ++nn)                                        \
                _Pragma("unroll")                                                 \
                for (int qt = 0; qt < 2; ++qt)                                    \
                    acc[nn][qt] = __builtin_amdgcn_mfma_f32_16x16x32_bf16(        \
                        A_, Bq[nn][qt][s], acc[nn][qt], 0, 0, 0);                 \
        }                                                                         \
        if (!(MASKED) || lg < 2) {                                                \
            _Pragma("unroll")                                                     \
            for (int nn = 0; nn < 2; ++nn)                                        \
                _Pragma("unroll")                                                 \
                for (int qt = 0; qt < 2; ++qt)                                    \
                    qmax[nn][qt] = fmaxf(qmax[nn][qt],                            \
                        fmaxf(fmaxf(acc[nn][qt][0], acc[nn][qt][1]),              \
                              fmaxf(acc[nn][qt][2], acc[nn][qt][3])));            \
        }                                                                         \
    }

    #pragma unroll
    for (int dt = 0; dt < 12; ++dt) STEP(dt, false);
    STEP(12, true);   // rows 192..199 valid only for lg<2 (200..207 are zero pad)
#undef STEP

    // max over d: combine the 4 lg groups (lanes ^16, ^32)
    #pragma unroll
    for (int off = 16; off <= 32; off <<= 1)
        #pragma unroll
        for (int nn = 0; nn < 2; ++nn)
            #pragma unroll
            for (int qt = 0; qt < 2; ++qt)
                qmax[nn][qt] = fmaxf(qmax[nn][qt], __shfl_xor(qmax[nn][qt], off, 64));

    // mean over q: qt0 + qt1, then sum across the 16 lr lanes
    float s0 = qmax[0][0] + qmax[0][1];
    float s1 = qmax[1][0] + qmax[1][1];
    #pragma unroll
    for (int off = 1; off <= 8; off <<= 1) {
        s0 += __shfl_xor(s0, off, 64);
        s1 += __shfl_xor(s1, off, 64);
    }
    if (lane == 0) {
        out[(size_t)n0 * MD + m] = s0 * (1.0f / 32.0f);
        out[(size_t)(n0 + 1) * MD + m] = s1 * (1.0f / 32.0f);
    }
}

// loss = mean_n( logsumexp(row_n) - row_n[8n] )
__global__ __launch_bounds__(256) void colbert_loss(const float* __restrict__ scores,
                                                    float* __restrict__ loss_out) {
    __shared__ float terms[NQ];
    const int tid = threadIdx.x;
    const int wid = tid >> 6, lane = tid & 63;
    for (int n = wid; n < NQ; n += 4) {
        const float* row = scores + n * MD;
        float v0 = row[lane], v1 = row[64 + lane], v2 = row[128 + lane], v3 = row[192 + lane];
        float mx = fmaxf(fmaxf(v0, v1), fmaxf(v2, v3));
        #pragma unroll
        for (int off = 1; off < 64; off <<= 1) mx = fmaxf(mx, __shfl_xor(mx, off, 64));
        float s = expf(v0 - mx) + expf(v1 - mx) + expf(v2 - mx) + expf(v3 - mx);
        #pragma unroll
        for (int off = 1; off < 64; off <<= 1) s += __shfl_xor(s, off, 64);
        if (lane == 0) terms[n] = (mx + logf(s)) - row[n * NDOCS];
    }
    __syncthreads();
    if (tid == 0) {
        float acc = 0.f;
        #pragma unroll
        for (int n = 0; n < NQ; ++n) acc += terms[n];
        loss_out[0] = acc * (1.0f / NQ);
    }
}

extern "C" void kernel_launch(void* const* d_in, const int* in_sizes, int n_in,
                              void* d_out, int out_size, void* d_ws, size_t ws_size,
                              hipStream_t stream) {
    const float* hq = (const float*)d_in[0];   // [32][32][128] f32
    const float* hd = (const float*)d_in[1];   // [256][200][128] f32
    float* out = (float*)d_out;                // 8192 scores + 1 loss
    short* hdb = (short*)d_ws;                 // 256 docs x 208 rows x 128 bf16 (pre-swizzled)

    convert_hd<<<3328, 256, 0, stream>>>(hd, hdb);
    colbert_scores<<<512, 512, 0, stream>>>(hq, hdb, out);
    colbert_loss<<<1, 256, 0, stream>>>(out, out + NQ * MD);
}

// Round 9
// 40.897 us; speedup vs baseline: 2.0378x; 1.4530x over previous
//
#include <hip/hip_runtime.h>
#include <hip/hip_bf16.h>
#include <math.h>

typedef short short8 __attribute__((ext_vector_type(8)));
typedef float f32x4 __attribute__((ext_vector_type(4)));

#define NQ 32
#define NDOCS 8
#define QLEN 32
#define DLEN 200
#define DIM 128
#define MD 256            // total docs
#define HD_ROWS 208       // 200 real + 8 zero pad rows
#define DOC_SHORTS (HD_ROWS * DIM)      // 26624 bf16 = 53248 B per doc
#define DOC_BYTES (DOC_SHORTS * 2)      // 53248
#define DOC_CHUNKS (HD_ROWS * 16)       // 3328 16B-chunks per doc

__device__ __forceinline__ short f2bf(float x) {
    union { float f; unsigned u; } v; v.f = x;
    unsigned r = v.u + 0x7FFFu + ((v.u >> 16) & 1u);  // RNE
    return (short)(r >> 16);
}

__device__ __forceinline__ short8 cvt8(float4 f0, float4 f1) {
    short8 o;
    o[0] = f2bf(f0.x); o[1] = f2bf(f0.y); o[2] = f2bf(f0.z); o[3] = f2bf(f0.w);
    o[4] = f2bf(f1.x); o[5] = f2bf(f1.y); o[6] = f2bf(f1.z); o[7] = f2bf(f1.w);
    return o;
}

// hd fp32 -> bf16, PRE-SWIZZLED in global (chunk kc -> kc ^ (row&7) within each row),
// pad rows 200..207 zeroed. Scores kernel then copies linearly into LDS
// (global_load_lds requirement) and applies the XOR on ds_read (rule: swizzle
// source + read, keep LDS dest linear).
__global__ __launch_bounds__(256) void convert_hd(const float* __restrict__ hd,
                                                  short* __restrict__ hdb) {
    unsigned c = blockIdx.x * 256 + threadIdx.x;       // global chunk id, < 851968
    unsigned m = c / DOC_CHUNKS;
    unsigned rc = c - m * DOC_CHUNKS;
    unsigned row = rc >> 4, kc = rc & 15;
    short8 o = {0, 0, 0, 0, 0, 0, 0, 0};
    if (row < DLEN) {
        const float4* p = reinterpret_cast<const float4*>(
            hd + ((size_t)m * DLEN + row) * DIM + kc * 8);
        o = cvt8(p[0], p[1]);
    }
    unsigned dst = m * DOC_CHUNKS + row * 16 + (kc ^ (row & 7));
    reinterpret_cast<short8*>(hdb)[dst] = o;
}

// grid = 2048: b = qg*256 + m  (b = m mod 8 -> all 8 blocks of doc m on one XCD).
// Block: 256 thr / 4 waves; wave wid computes question n = qg*4 + wid.
// Staging: 13x global_load_lds (16B/lane) -> zero staging VGPRs; live set ~55 < 64
// so the compiler's 8-waves/EU 64-VGPR target cannot spill.
// C = mfma(A=hd_frag, B=hq_frag): lane holds C[d = dt*16 + lg*4 + r][q = qt*16 + lr].
__global__ __launch_bounds__(256) void colbert_scores(const float* __restrict__ hq,
                                                      const short* __restrict__ hdb,
                                                      float* __restrict__ out) {
    __shared__ char lds[DOC_BYTES];   // 53248 B -> 3 blocks/CU
    const int tid = threadIdx.x;
    const int b = blockIdx.x;
    const int m = b & 255, qg = b >> 8;
    const int wid = tid >> 6, lane = tid & 63;
    const int lg = lane >> 4, lr = lane & 15;
    const int n = qg * 4 + wid;

    // ---- 1) stage doc m via direct HBM/L2 -> LDS DMA (no VGPRs, async) ----
    const char* gsrc = reinterpret_cast<const char*>(hdb + (size_t)m * DOC_SHORTS);
    {
        const int gbase = wid * 1024 + lane * 16;
        #pragma unroll
        for (int i = 0; i < 13; ++i)
            __builtin_amdgcn_global_load_lds(
                (const __attribute__((address_space(1))) void*)(gsrc + i * 4096 + gbase),
                (__attribute__((address_space(3))) void*)(lds + i * 4096 + wid * 1024),
                16, 0, 0);
    }

    // ---- 2) Bq for question n (fp32 -> bf16 inline), overlapped with staging ----
    short8 Bq[2][4];
    #pragma unroll
    for (int qt = 0; qt < 2; ++qt)
        #pragma unroll
        for (int s = 0; s < 4; ++s) {
            const float4* p = reinterpret_cast<const float4*>(
                hq + (size_t)(n * QLEN + qt * 16 + lr) * DIM + s * 32 + lg * 8);
            Bq[qt][s] = cvt8(p[0], p[1]);
        }

    __syncthreads();   // drains vmcnt (incl. global_load_lds) + barrier

    // ---- 3) compute: 13 tiles x (4 ds_read_b128 + 8 MFMA) ----
    int va[4];
    #pragma unroll
    for (int s = 0; s < 4; ++s)
        va[s] = lr * 256 + ((s * 64 + lg * 16) ^ ((lr & 7) << 4));

    float qmax0 = -INFINITY, qmax1 = -INFINITY;

#define STEP(DT, MASKED)                                                          \
    {                                                                             \
        f32x4 a0 = {0.f, 0.f, 0.f, 0.f}, a1 = {0.f, 0.f, 0.f, 0.f};               \
        _Pragma("unroll")                                                         \
        for (int s = 0; s < 4; ++s) {                                             \
            short8 A_ = *reinterpret_cast<const short8*>(&lds[va[s] + (DT) * 4096]); \
            a0 = __builtin_amdgcn_mfma_f32_16x16x32_bf16(A_, Bq[0][s], a0, 0, 0, 0); \
            a1 = __builtin_amdgcn_mfma_f32_16x16x32_bf16(A_, Bq[1][s], a1, 0, 0, 0); \
        }                                                                         \
        if (!(MASKED) || lg < 2) {                                                \
            qmax0 = fmaxf(qmax0, fmaxf(fmaxf(a0[0], a0[1]), fmaxf(a0[2], a0[3])));\
            qmax1 = fmaxf(qmax1, fmaxf(fmaxf(a1[0], a1[1]), fmaxf(a1[2], a1[3])));\
        }                                                                         \
    }

    #pragma unroll
    for (int dt = 0; dt < 12; ++dt) STEP(dt, false);
    STEP(12, true);   // rows 192..199 valid only for lg<2 (200..207 are zero pad)
#undef STEP

    // max over d: combine the 4 lg groups (lanes ^16, ^32)
    #pragma unroll
    for (int off = 16; off <= 32; off <<= 1) {
        qmax0 = fmaxf(qmax0, __shfl_xor(qmax0, off, 64));
        qmax1 = fmaxf(qmax1, __shfl_xor(qmax1, off, 64));
    }
    // mean over q: this lane's q = lr and q = 16+lr, then sum across the 16 lr lanes
    float s = qmax0 + qmax1;
    #pragma unroll
    for (int off = 1; off <= 8; off <<= 1) s += __shfl_xor(s, off, 64);
    if (lane == 0) out[(size_t)n * MD + m] = s * (1.0f / 32.0f);
}

// loss = mean_n( logsumexp(row_n) - row_n[8n] )
__global__ __launch_bounds__(256) void colbert_loss(const float* __restrict__ scores,
                                                    float* __restrict__ loss_out) {
    __shared__ float terms[NQ];
    const int tid = threadIdx.x;
    const int wid = tid >> 6, lane = tid & 63;
    for (int n = wid; n < NQ; n += 4) {
        const float* row = scores + n * MD;
        float v0 = row[lane], v1 = row[64 + lane], v2 = row[128 + lane], v3 = row[192 + lane];
        float mx = fmaxf(fmaxf(v0, v1), fmaxf(v2, v3));
        #pragma unroll
        for (int off = 1; off < 64; off <<= 1) mx = fmaxf(mx, __shfl_xor(mx, off, 64));
        float s = expf(v0 - mx) + expf(v1 - mx) + expf(v2 - mx) + expf(v3 - mx);
        #pragma unroll
        for (int off = 1; off < 64; off <<= 1) s += __shfl_xor(s, off, 64);
        if (lane == 0) terms[n] = (mx + logf(s)) - row[n * NDOCS];
    }
    __syncthreads();
    if (tid == 0) {
        float acc = 0.f;
        #pragma unroll
        for (int n = 0; n < NQ; ++n) acc += terms[n];
        loss_out[0] = acc * (1.0f / NQ);
    }
}

extern "C" void kernel_launch(void* const* d_in, const int* in_sizes, int n_in,
                              void* d_out, int out_size, void* d_ws, size_t ws_size,
                              hipStream_t stream) {
    const float* hq = (const float*)d_in[0];   // [32][32][128] f32
    const float* hd = (const float*)d_in[1];   // [256][200][128] f32
    float* out = (float*)d_out;                // 8192 scores + 1 loss
    short* hdb = (short*)d_ws;                 // 256 docs x 208 rows x 128 bf16 (pre-swizzled)

    convert_hd<<<3328, 256, 0, stream>>>(hd, hdb);
    colbert_scores<<<2048, 256, 0, stream>>>(hq, hdb, out);
    colbert_loss<<<1, 256, 0, stream>>>(out, out + NQ * MD);
}